// Round 4
// baseline (645.427 us; speedup 1.0000x reference)
//
#include <hip/hip_runtime.h>

#define BIG_NEG_F (-4294967296.0f)

__device__ __forceinline__ unsigned short f2bf(float f) {
    union { float f; unsigned int i; } u; u.f = f;
    return (unsigned short)((u.i + 0x7fffu + ((u.i >> 16) & 1u)) >> 16);
}

// Detect mask storage layout (uint8 / int32 / int64 bool) and normalize to uint8[2048].
__global__ __launch_bounds__(256) void mask_norm_kernel(const unsigned char* __restrict__ m,
                                                        unsigned char* __restrict__ out) {
    __shared__ int flags[2];
    if (threadIdx.x == 0) { flags[0] = 0; flags[1] = 0; }
    __syncthreads();
    for (int i = threadIdx.x; i < 2048; i += 256) {
        if (m[i]) {
            if (i & 3) atomicOr(&flags[0], 1);
            else if (i & 4) atomicOr(&flags[1], 1);
        }
    }
    __syncthreads();
    int mode = flags[0] ? 0 : (flags[1] ? 1 : 2);  // 0=u8, 1=i32, 2=i64
    for (int i = threadIdx.x; i < 2048; i += 256) {
        unsigned char v = (mode == 0) ? m[i] : (mode == 1) ? m[i * 4] : m[i * 8];
        out[i] = v ? 1 : 0;
    }
}

// x = seq_emb * keep   (fp32 in, fp32 out)
__global__ __launch_bounds__(256) void prep_kernel(const float* __restrict__ seq,
                                                   const unsigned char* __restrict__ mask,
                                                   float* __restrict__ x) {
    int i = blockIdx.x * 256 + threadIdx.x;
    x[i] = mask[i >> 8] ? 0.f : seq[i];
}

// row layernorm over H=256, one block per row  (fp32 out always)
__global__ __launch_bounds__(256) void ln_kernel(const float* __restrict__ X, float* __restrict__ Y,
                                                 const float* __restrict__ g,
                                                 const float* __restrict__ be) {
    __shared__ float red[256];
    int row = blockIdx.x, tid = threadIdx.x;
    int idx = row * 256 + tid;
    float v = X[idx];
    red[tid] = v; __syncthreads();
    for (int off = 128; off; off >>= 1) { if (tid < off) red[tid] += red[tid + off]; __syncthreads(); }
    float mean = red[0] * (1.f / 256.f);
    __syncthreads();
    float d = v - mean;
    red[tid] = d * d; __syncthreads();
    for (int off = 128; off; off >>= 1) { if (tid < off) red[tid] += red[tid + off]; __syncthreads(); }
    float var = red[0] * (1.f / 256.f);
    Y[idx] = d / sqrtf(var + 1e-8f) * g[tid] + be[tid];
}

// C[M=2048, N=256] = A[M,256] @ W[N,256]^T + bias  (+pos[l]) (relu) (+res) (*keep)
__global__ __launch_bounds__(256) void gemm_kernel(
    const float* __restrict__ A, const float* __restrict__ W,
    const float* __restrict__ bias, const float* __restrict__ pos,
    const float* __restrict__ res, const unsigned char* __restrict__ maskm,
    float* __restrict__ C, int relu) {
    __shared__ float As[64][17];
    __shared__ float Ws[64][17];
    int tid = threadIdx.x;
    int n0 = blockIdx.x * 64, m0 = blockIdx.y * 64;
    int r = tid >> 4, c = tid & 15;
    int li = tid >> 2;          // tile row for cooperative loads (tid/4)
    int lk = (tid & 3) * 4;     // tile k   (multiple of 4)
    float acc[4][4] = {};
    for (int k0 = 0; k0 < 256; k0 += 16) {
        float4 av = *(const float4*)(A + (m0 + li) * 256 + k0 + lk);
        As[li][lk + 0] = av.x; As[li][lk + 1] = av.y; As[li][lk + 2] = av.z; As[li][lk + 3] = av.w;
        float4 wv = *(const float4*)(W + (n0 + li) * 256 + k0 + lk);
        Ws[li][lk + 0] = wv.x; Ws[li][lk + 1] = wv.y; Ws[li][lk + 2] = wv.z; Ws[li][lk + 3] = wv.w;
        __syncthreads();
#pragma unroll
        for (int kk = 0; kk < 16; ++kk) {
            float a[4], b[4];
#pragma unroll
            for (int i = 0; i < 4; ++i) a[i] = As[r * 4 + i][kk];
#pragma unroll
            for (int j = 0; j < 4; ++j) b[j] = Ws[c * 4 + j][kk];
#pragma unroll
            for (int i = 0; i < 4; ++i)
#pragma unroll
                for (int j = 0; j < 4; ++j) acc[i][j] += a[i] * b[j];
        }
        __syncthreads();
    }
#pragma unroll
    for (int i = 0; i < 4; ++i) {
        int m = m0 + r * 4 + i;
#pragma unroll
        for (int j = 0; j < 4; ++j) {
            int n = n0 + c * 4 + j;
            float v = acc[i][j] + bias[n];
            if (pos) v += pos[(m & 255) * 256 + n];
            if (relu) v = fmaxf(v, 0.f);
            if (res) v += res[m * 256 + n];
            if (maskm && maskm[m]) v = 0.f;
            C[m * 256 + n] = v;
        }
    }
}

// one block per (q, head, batch): scores (K' + gathered tK), softmax, out (V' + gathered tV)
// writes X[b,q,h*64+d] = qres + attn_out
__global__ __launch_bounds__(256) void attn_kernel(
    const float* __restrict__ Q, const float* __restrict__ Kp, const float* __restrict__ Vp,
    const float* __restrict__ qres, const int* __restrict__ tm,
    const float* __restrict__ tK, const float* __restrict__ tV,
    const unsigned char* __restrict__ mask, float* __restrict__ X) {
    int qpos = blockIdx.x, h = blockIdx.y, b = blockIdx.z;
    int tid = threadIdx.x;
    __shared__ float qrow[64];
    __shared__ float p[256];
    __shared__ int   stm[256];
    __shared__ float red[256];
    int hoff = h * 64;
    int rowbase = (b * 256 + qpos) * 256 + hoff;
    if (tid < 64) qrow[tid] = Q[rowbase + tid];
    {
        int t = tm[(b * 256 + qpos) * 256 + tid];
        stm[tid] = t < 0 ? 0 : (t > 512 ? 512 : t);   // clamp: OOB-gather insurance
    }
    __syncthreads();

    // --- scores: thread k
    int k = tid;
    int mq = mask[b * 256 + qpos];
    float s;
    if (k > qpos || mq) {
        s = BIG_NEG_F;
    } else {
        const float* krow = Kp + (b * 256 + k) * 256 + hoff;
        const float* trow = tK + stm[k] * 256 + hoff;
        float acc = 0.f;
#pragma unroll
        for (int j = 0; j < 64; j += 4) {
            float4 kv = *(const float4*)(krow + j);
            float4 t4 = *(const float4*)(trow + j);
            acc += qrow[j + 0] * (kv.x + t4.x);
            acc += qrow[j + 1] * (kv.y + t4.y);
            acc += qrow[j + 2] * (kv.z + t4.z);
            acc += qrow[j + 3] * (kv.w + t4.w);
        }
        s = acc * 0.125f;  // / sqrt(64)
    }

    // --- softmax (unnormalized p, divide at end)
    red[tid] = s; __syncthreads();
    for (int off = 128; off; off >>= 1) { if (tid < off) red[tid] = fmaxf(red[tid], red[tid + off]); __syncthreads(); }
    float mx = red[0]; __syncthreads();
    float e = expf(s - mx);
    p[tid] = e; red[tid] = e; __syncthreads();
    for (int off = 128; off; off >>= 1) { if (tid < off) red[tid] += red[tid + off]; __syncthreads(); }
    float denom = red[0]; __syncthreads();

    // --- output: thread = (kk = tid/64 chunk of k, d = tid%64)
    int kk = tid >> 6, d = tid & 63;
    float o = 0.f;
    for (int kl = 0; kl < 64; ++kl) {
        int k2 = (kk << 6) + kl;
        float pk = p[k2];
        if (pk != 0.f) {   // uniform across the 64-lane d-group -> no divergence
            float v = Vp[(b * 256 + k2) * 256 + hoff + d];
            float t = tV[stm[k2] * 256 + hoff + d];
            o += pk * (v + t);
        }
    }
    red[tid] = o; __syncthreads();
    if (tid < 64) {
        float tot = (red[tid] + red[tid + 64] + red[tid + 128] + red[tid + 192]) / denom;
        X[rowbase + tid] = qres[rowbase + tid] + tot;
    }
}

extern "C" void kernel_launch(void* const* d_in, const int* in_sizes, int n_in,
                              void* d_out, int out_size, void* d_ws, size_t ws_size,
                              hipStream_t stream) {
    const unsigned char* mask_raw = (const unsigned char*)d_in[0];
    const float* seq  = (const float*)d_in[1];
    // d_in[2] log_seqs, d_in[4] time_attn: unused
    const int*   tm   = (const int*)d_in[3];
    const float* Wq   = (const float*)d_in[5];
    const float* bq   = (const float*)d_in[6];
    const float* Wk   = (const float*)d_in[7];
    const float* bk   = (const float*)d_in[8];
    const float* Wv   = (const float*)d_in[9];
    const float* bv   = (const float*)d_in[10];
    const float* ln1g = (const float*)d_in[11];
    const float* ln1b = (const float*)d_in[12];
    const float* ln2g = (const float*)d_in[13];
    const float* ln2b = (const float*)d_in[14];
    const float* W1   = (const float*)d_in[15];
    const float* b1   = (const float*)d_in[16];
    const float* W2   = (const float*)d_in[17];
    const float* b2   = (const float*)d_in[18];
    const float* posK = (const float*)d_in[19];
    const float* posV = (const float*)d_in[20];
    const float* tK   = (const float*)d_in[21];
    const float* tV   = (const float*)d_in[22];
    const float* lnfg = (const float*)d_in[23];
    const float* lnfb = (const float*)d_in[24];

    const int NEL = 8 * 256 * 256;  // 524288
    float* x   = (float*)d_ws;
    float* q   = x   + NEL;
    float* Qb  = q   + NEL;
    float* KpB = Qb  + NEL;
    float* VpB = KpB + NEL;
    float* x2  = VpB + NEL;
    float* hb  = x2  + NEL;
    unsigned char* mask = (unsigned char*)(hb + NEL);  // normalized uint8[2048]

    dim3 gGemm(4, 32);        // N/64, M/64
    dim3 gAttn(256, 4, 8);    // q, head, batch

    mask_norm_kernel<<<1, 256, 0, stream>>>(mask_raw, mask);
    prep_kernel<<<2048, 256, 0, stream>>>(seq, mask, x);
    for (int blk = 0; blk < 2; ++blk) {
        int o1 = blk * 256, oW = blk * 256 * 256;
        ln_kernel<<<2048, 256, 0, stream>>>(x, q, ln1g + o1, ln1b + o1);
        gemm_kernel<<<gGemm, 256, 0, stream>>>(q,  Wq + oW, bq + o1, nullptr, nullptr, nullptr, Qb,  0);
        gemm_kernel<<<gGemm, 256, 0, stream>>>(x,  Wk + oW, bk + o1, posK,    nullptr, nullptr, KpB, 0);
        gemm_kernel<<<gGemm, 256, 0, stream>>>(x,  Wv + oW, bv + o1, posV,    nullptr, nullptr, VpB, 0);
        attn_kernel<<<gAttn, 256, 0, stream>>>(Qb, KpB, VpB, q, tm, tK, tV, mask, x);
        ln_kernel<<<2048, 256, 0, stream>>>(x, x2, ln2g + o1, ln2b + o1);
        gemm_kernel<<<gGemm, 256, 0, stream>>>(x2, W1 + oW, b1 + o1, nullptr, nullptr, nullptr, hb, 1);
        gemm_kernel<<<gGemm, 256, 0, stream>>>(hb, W2 + oW, b2 + o1, nullptr, x2,      mask,    x,  0);
    }
    ln_kernel<<<2048, 256, 0, stream>>>(x, (float*)d_out, lnfg, lnfb);
}

// Round 5
// 521.290 us; speedup vs baseline: 1.2381x; 1.2381x over previous
//
#include <hip/hip_runtime.h>

#define BIG_NEG_F (-4294967296.0f)

__device__ __forceinline__ float wave_sum(float v) {
#pragma unroll
    for (int m = 32; m; m >>= 1) v += __shfl_xor(v, m, 64);
    return v;
}
__device__ __forceinline__ float wave_max(float v) {
#pragma unroll
    for (int m = 32; m; m >>= 1) v = fmaxf(v, __shfl_xor(v, m, 64));
    return v;
}

// Detect mask storage layout (uint8 / int32 / int64 bool) and normalize to uint8[2048].
__global__ __launch_bounds__(256) void mask_norm_kernel(const unsigned char* __restrict__ m,
                                                        unsigned char* __restrict__ out) {
    __shared__ int flags[2];
    if (threadIdx.x == 0) { flags[0] = 0; flags[1] = 0; }
    __syncthreads();
    for (int i = threadIdx.x; i < 2048; i += 256) {
        if (m[i]) {
            if (i & 3) atomicOr(&flags[0], 1);
            else if (i & 4) atomicOr(&flags[1], 1);
        }
    }
    __syncthreads();
    int mode = flags[0] ? 0 : (flags[1] ? 1 : 2);  // 0=u8, 1=i32, 2=i64
    for (int i = threadIdx.x; i < 2048; i += 256) {
        unsigned char v = (mode == 0) ? m[i] : (mode == 1) ? m[i * 4] : m[i * 8];
        out[i] = v ? 1 : 0;
    }
}

__global__ __launch_bounds__(256) void prep_kernel(const float* __restrict__ seq,
                                                   const unsigned char* __restrict__ mask,
                                                   float* __restrict__ x) {
    int i = blockIdx.x * 256 + threadIdx.x;
    x[i] = mask[i >> 8] ? 0.f : seq[i];
}

// row layernorm over H=256, one block per row; shfl reductions (2 barriers)
__global__ __launch_bounds__(256) void ln_kernel(const float* __restrict__ X, float* __restrict__ Y,
                                                 const float* __restrict__ g,
                                                 const float* __restrict__ be) {
    __shared__ float ws[8];
    int row = blockIdx.x, tid = threadIdx.x;
    int idx = row * 256 + tid;
    int w = tid >> 6, lane = tid & 63;
    float v = X[idx];
    float s = wave_sum(v);
    if (lane == 0) ws[w] = s;
    __syncthreads();
    float mean = (ws[0] + ws[1] + ws[2] + ws[3]) * (1.f / 256.f);
    float d = v - mean;
    float s2 = wave_sum(d * d);
    if (lane == 0) ws[4 + w] = s2;
    __syncthreads();
    float var = (ws[4] + ws[5] + ws[6] + ws[7]) * (1.f / 256.f);
    Y[idx] = d / sqrtf(var + 1e-8f) * g[tid] + be[tid];
}

struct GemmJob {
    const float* A;     // [2048,256]
    const float* W;     // [256,256] row-major (out,in)
    const float* bias;  // [256]
    const float* pos;   // [256,256] per-position add, or null
    float* C;           // [2048,256]
};

// C = A @ W^T + bias (+pos[l]) (relu) (+res) (*keep).  32x32 tile, BK=32, 512 blocks/z.
__global__ __launch_bounds__(256) void gemm_kernel(GemmJob j0, GemmJob j1, GemmJob j2,
                                                   const float* __restrict__ res,
                                                   const unsigned char* __restrict__ maskm,
                                                   int relu) {
    GemmJob J = (blockIdx.z == 0) ? j0 : (blockIdx.z == 1 ? j1 : j2);
    __shared__ float AsT[32][34];   // [k][m], pad 34: 8B-aligned float2 rows, 2-way max conflicts
    __shared__ float WsT[32][34];   // [k][n]
    int tid = threadIdx.x;
    int n0 = blockIdx.x * 32, m0 = blockIdx.y * 32;
    int r = tid >> 4, c = tid & 15;        // 16x16 threads, 2x2 outputs each
    int li = tid >> 3, lk = (tid & 7) * 4; // cooperative load: row li, k-offset lk
    float acc00 = 0, acc01 = 0, acc10 = 0, acc11 = 0;
    for (int k0 = 0; k0 < 256; k0 += 32) {
        float4 av = *(const float4*)(J.A + (m0 + li) * 256 + k0 + lk);
        AsT[lk + 0][li] = av.x; AsT[lk + 1][li] = av.y; AsT[lk + 2][li] = av.z; AsT[lk + 3][li] = av.w;
        float4 wv = *(const float4*)(J.W + (n0 + li) * 256 + k0 + lk);
        WsT[lk + 0][li] = wv.x; WsT[lk + 1][li] = wv.y; WsT[lk + 2][li] = wv.z; WsT[lk + 3][li] = wv.w;
        __syncthreads();
#pragma unroll
        for (int kk = 0; kk < 32; ++kk) {
            float2 a = *(const float2*)&AsT[kk][r * 2];
            float2 b = *(const float2*)&WsT[kk][c * 2];
            acc00 += a.x * b.x; acc01 += a.x * b.y;
            acc10 += a.y * b.x; acc11 += a.y * b.y;
        }
        __syncthreads();
    }
    float accs[2][2] = {{acc00, acc01}, {acc10, acc11}};
#pragma unroll
    for (int i = 0; i < 2; ++i) {
        int m = m0 + r * 2 + i;
#pragma unroll
        for (int jj = 0; jj < 2; ++jj) {
            int n = n0 + c * 2 + jj;
            float v = accs[i][jj] + J.bias[n];
            if (J.pos) v += J.pos[(m & 255) * 256 + n];
            if (relu) v = fmaxf(v, 0.f);
            if (res) v += res[m * 256 + n];
            if (maskm && maskm[m]) v = 0.f;
            J.C[m * 256 + n] = v;
        }
    }
}

// one block per (b,q), all 4 heads. scores -> shfl softmax -> gathered PV. X = qres + out.
__global__ __launch_bounds__(256) void attn_kernel(
    const float* __restrict__ Q, const float* __restrict__ Kp, const float* __restrict__ Vp,
    const float* __restrict__ qres, const int* __restrict__ tm,
    const float* __restrict__ tK, const float* __restrict__ tV,
    float* __restrict__ X) {
    int qpos = blockIdx.x, b = blockIdx.y;
    int tid = threadIdx.x;
    __shared__ float qrow[256];
    __shared__ int   stm[256];
    __shared__ float p[4 * 256];
    __shared__ float denom[4];
    int rowbase = (b * 256 + qpos) * 256;
    qrow[tid] = Q[rowbase + tid];
    {
        int t = tm[(b * 256 + qpos) * 256 + tid];
        stm[tid] = t < 0 ? 0 : (t > 512 ? 512 : t);
    }
    __syncthreads();

    // --- scores: thread k computes all 4 head dots over its K/tK rows (rows read once)
    {
        int k = tid;
        float s[4];
        if (k <= qpos) {
            const float* krow = Kp + (b * 256 + k) * 256;
            const float* trow = tK + stm[k] * 256;
            for (int h = 0; h < 4; ++h) {
                const float* kr = krow + h * 64;
                const float* tr = trow + h * 64;
                const float* qr = qrow + h * 64;
                float a = 0.f;
#pragma unroll 4
                for (int d = 0; d < 64; d += 4) {
                    float4 kv = *(const float4*)(kr + d);
                    float4 t4 = *(const float4*)(tr + d);
                    a += qr[d + 0] * (kv.x + t4.x);
                    a += qr[d + 1] * (kv.y + t4.y);
                    a += qr[d + 2] * (kv.z + t4.z);
                    a += qr[d + 3] * (kv.w + t4.w);
                }
                s[h] = a * 0.125f;
            }
        } else {
            s[0] = s[1] = s[2] = s[3] = BIG_NEG_F;
        }
#pragma unroll
        for (int h = 0; h < 4; ++h) p[h * 256 + k] = s[h];
    }
    __syncthreads();

    // --- softmax: wave w owns head w (4 vals/lane, shfl reduce)
    {
        int w = tid >> 6, lane = tid & 63;
        float* ph = p + w * 256;
        float v0 = ph[lane], v1 = ph[lane + 64], v2 = ph[lane + 128], v3 = ph[lane + 192];
        float mx = wave_max(fmaxf(fmaxf(v0, v1), fmaxf(v2, v3)));
        float e0 = __expf(v0 - mx), e1 = __expf(v1 - mx), e2 = __expf(v2 - mx), e3 = __expf(v3 - mx);
        ph[lane] = e0; ph[lane + 64] = e1; ph[lane + 128] = e2; ph[lane + 192] = e3;
        float ssum = wave_sum(e0 + e1 + e2 + e3);
        if (lane == 0) denom[w] = ssum;
    }
    __syncthreads();

    // --- output: thread d (head h = d>>6); coalesced V/tV rows, broadcast p
    {
        int d = tid, h = tid >> 6;
        const float* ph = p + h * 256;
        float o = 0.f;
#pragma unroll 4
        for (int k2 = 0; k2 <= qpos; ++k2) {
            float pk = ph[k2];
            float v = Vp[(b * 256 + k2) * 256 + d];
            float t = tV[stm[k2] * 256 + d];
            o += pk * (v + t);
        }
        X[rowbase + d] = qres[rowbase + d] + o / denom[h];
    }
}

extern "C" void kernel_launch(void* const* d_in, const int* in_sizes, int n_in,
                              void* d_out, int out_size, void* d_ws, size_t ws_size,
                              hipStream_t stream) {
    const unsigned char* mask_raw = (const unsigned char*)d_in[0];
    const float* seq  = (const float*)d_in[1];
    const int*   tm   = (const int*)d_in[3];
    const float* Wq   = (const float*)d_in[5];
    const float* bq   = (const float*)d_in[6];
    const float* Wk   = (const float*)d_in[7];
    const float* bk   = (const float*)d_in[8];
    const float* Wv   = (const float*)d_in[9];
    const float* bv   = (const float*)d_in[10];
    const float* ln1g = (const float*)d_in[11];
    const float* ln1b = (const float*)d_in[12];
    const float* ln2g = (const float*)d_in[13];
    const float* ln2b = (const float*)d_in[14];
    const float* W1   = (const float*)d_in[15];
    const float* b1   = (const float*)d_in[16];
    const float* W2   = (const float*)d_in[17];
    const float* b2   = (const float*)d_in[18];
    const float* posK = (const float*)d_in[19];
    const float* posV = (const float*)d_in[20];
    const float* tK   = (const float*)d_in[21];
    const float* tV   = (const float*)d_in[22];
    const float* lnfg = (const float*)d_in[23];
    const float* lnfb = (const float*)d_in[24];

    const int NEL = 8 * 256 * 256;
    float* x   = (float*)d_ws;
    float* q   = x   + NEL;
    float* Qb  = q   + NEL;
    float* KpB = Qb  + NEL;
    float* VpB = KpB + NEL;
    float* x2  = VpB + NEL;
    float* hb  = x2  + NEL;
    unsigned char* mask = (unsigned char*)(hb + NEL);

    dim3 gQKV(8, 64, 3);
    dim3 gFFN(8, 64, 1);
    dim3 gAttn(256, 8);

    mask_norm_kernel<<<1, 256, 0, stream>>>(mask_raw, mask);
    prep_kernel<<<2048, 256, 0, stream>>>(seq, mask, x);
    for (int blk = 0; blk < 2; ++blk) {
        int o1 = blk * 256, oW = blk * 256 * 256;
        ln_kernel<<<2048, 256, 0, stream>>>(x, q, ln1g + o1, ln1b + o1);
        GemmJob jq = {q, Wq + oW, bq + o1, nullptr, Qb};
        GemmJob jk = {x, Wk + oW, bk + o1, posK,    KpB};
        GemmJob jv = {x, Wv + oW, bv + o1, posV,    VpB};
        gemm_kernel<<<gQKV, 256, 0, stream>>>(jq, jk, jv, nullptr, nullptr, 0);
        attn_kernel<<<gAttn, 256, 0, stream>>>(Qb, KpB, VpB, q, tm, tK, tV, x);
        ln_kernel<<<2048, 256, 0, stream>>>(x, x2, ln2g + o1, ln2b + o1);
        GemmJob jf1 = {x2, W1 + oW, b1 + o1, nullptr, hb};
        gemm_kernel<<<gFFN, 256, 0, stream>>>(jf1, jf1, jf1, nullptr, nullptr, 1);
        GemmJob jf2 = {hb, W2 + oW, b2 + o1, nullptr, x};
        gemm_kernel<<<gFFN, 256, 0, stream>>>(jf2, jf2, jf2, x2, mask, 0);
    }
    ln_kernel<<<2048, 256, 0, stream>>>(x, (float*)d_out, lnfg, lnfb);
}

// Round 6
// 368.554 us; speedup vs baseline: 1.7512x; 1.4144x over previous
//
#include <hip/hip_runtime.h>

#define BIG_NEG_F (-4294967296.0f)

__device__ __forceinline__ float wave_sum(float v) {
#pragma unroll
    for (int m = 32; m; m >>= 1) v += __shfl_xor(v, m, 64);
    return v;
}
__device__ __forceinline__ float wave_max(float v) {
#pragma unroll
    for (int m = 32; m; m >>= 1) v = fmaxf(v, __shfl_xor(v, m, 64));
    return v;
}

// Detect mask storage layout (uint8 / int32 / int64 bool) and normalize to uint8[2048].
__global__ __launch_bounds__(256) void mask_norm_kernel(const unsigned char* __restrict__ m,
                                                        unsigned char* __restrict__ out) {
    __shared__ int flags[2];
    if (threadIdx.x == 0) { flags[0] = 0; flags[1] = 0; }
    __syncthreads();
    for (int i = threadIdx.x; i < 2048; i += 256) {
        if (m[i]) {
            if (i & 3) atomicOr(&flags[0], 1);
            else if (i & 4) atomicOr(&flags[1], 1);
        }
    }
    __syncthreads();
    int mode = flags[0] ? 0 : (flags[1] ? 1 : 2);  // 0=u8, 1=i32, 2=i64
    for (int i = threadIdx.x; i < 2048; i += 256) {
        unsigned char v = (mode == 0) ? m[i] : (mode == 1) ? m[i * 4] : m[i * 8];
        out[i] = v ? 1 : 0;
    }
}

__global__ __launch_bounds__(256) void prep_kernel(const float* __restrict__ seq,
                                                   const unsigned char* __restrict__ mask,
                                                   float* __restrict__ x) {
    int i = blockIdx.x * 256 + threadIdx.x;
    x[i] = mask[i >> 8] ? 0.f : seq[i];
}

// row layernorm over H=256, one block per row; shfl reductions (2 barriers)
__global__ __launch_bounds__(256) void ln_kernel(const float* __restrict__ X, float* __restrict__ Y,
                                                 const float* __restrict__ g,
                                                 const float* __restrict__ be) {
    __shared__ float ws[8];
    int row = blockIdx.x, tid = threadIdx.x;
    int idx = row * 256 + tid;
    int w = tid >> 6, lane = tid & 63;
    float v = X[idx];
    float s = wave_sum(v);
    if (lane == 0) ws[w] = s;
    __syncthreads();
    float mean = (ws[0] + ws[1] + ws[2] + ws[3]) * (1.f / 256.f);
    float d = v - mean;
    float s2 = wave_sum(d * d);
    if (lane == 0) ws[4 + w] = s2;
    __syncthreads();
    float var = (ws[4] + ws[5] + ws[6] + ws[7]) * (1.f / 256.f);
    Y[idx] = d / sqrtf(var + 1e-8f) * g[tid] + be[tid];
}

struct GemmJob {
    const float* A;     // [2048,256]
    const float* W;     // [256,256] row-major (out,in)
    const float* bias;  // [256]
    const float* pos;   // [256,256] per-position add, or null
    float* C;           // [2048,256]
};

// C = A @ W^T + bias (+pos[l]) (relu) (+res) (*keep).  64x64 tile, 4x4/thread, BK=32.
__global__ __launch_bounds__(256) void gemm_kernel(GemmJob j0, GemmJob j1, GemmJob j2,
                                                   const float* __restrict__ res,
                                                   const unsigned char* __restrict__ maskm,
                                                   int relu) {
    GemmJob J = (blockIdx.z == 0) ? j0 : (blockIdx.z == 1 ? j1 : j2);
    __shared__ float AsT[32][68];   // [k][m]; 68: float4-aligned rows
    __shared__ float WsT[32][68];   // [k][n]
    int tid = threadIdx.x;
    int n0 = blockIdx.x * 64, m0 = blockIdx.y * 64;
    int r = tid >> 4, c = tid & 15;        // 16x16 threads, 4x4 outputs each
    int li = tid >> 2, lk = (tid & 3) * 8; // cooperative load: row li, k-offset lk (8 floats)
    float acc[4][4] = {};
    for (int k0 = 0; k0 < 256; k0 += 32) {
        float4 a0 = *(const float4*)(J.A + (m0 + li) * 256 + k0 + lk);
        float4 a1 = *(const float4*)(J.A + (m0 + li) * 256 + k0 + lk + 4);
        AsT[lk + 0][li] = a0.x; AsT[lk + 1][li] = a0.y; AsT[lk + 2][li] = a0.z; AsT[lk + 3][li] = a0.w;
        AsT[lk + 4][li] = a1.x; AsT[lk + 5][li] = a1.y; AsT[lk + 6][li] = a1.z; AsT[lk + 7][li] = a1.w;
        float4 w0 = *(const float4*)(J.W + (n0 + li) * 256 + k0 + lk);
        float4 w1 = *(const float4*)(J.W + (n0 + li) * 256 + k0 + lk + 4);
        WsT[lk + 0][li] = w0.x; WsT[lk + 1][li] = w0.y; WsT[lk + 2][li] = w0.z; WsT[lk + 3][li] = w0.w;
        WsT[lk + 4][li] = w1.x; WsT[lk + 5][li] = w1.y; WsT[lk + 6][li] = w1.z; WsT[lk + 7][li] = w1.w;
        __syncthreads();
#pragma unroll
        for (int kk = 0; kk < 32; ++kk) {
            float4 a = *(const float4*)&AsT[kk][r * 4];
            float4 bv = *(const float4*)&WsT[kk][c * 4];
            acc[0][0] += a.x * bv.x; acc[0][1] += a.x * bv.y; acc[0][2] += a.x * bv.z; acc[0][3] += a.x * bv.w;
            acc[1][0] += a.y * bv.x; acc[1][1] += a.y * bv.y; acc[1][2] += a.y * bv.z; acc[1][3] += a.y * bv.w;
            acc[2][0] += a.z * bv.x; acc[2][1] += a.z * bv.y; acc[2][2] += a.z * bv.z; acc[2][3] += a.z * bv.w;
            acc[3][0] += a.w * bv.x; acc[3][1] += a.w * bv.y; acc[3][2] += a.w * bv.z; acc[3][3] += a.w * bv.w;
        }
        __syncthreads();
    }
    int n = n0 + c * 4;
    float4 b4 = *(const float4*)(J.bias + n);
#pragma unroll
    for (int i = 0; i < 4; ++i) {
        int m = m0 + r * 4 + i;
        float4 v;
        v.x = acc[i][0] + b4.x; v.y = acc[i][1] + b4.y;
        v.z = acc[i][2] + b4.z; v.w = acc[i][3] + b4.w;
        if (J.pos) {
            float4 p4 = *(const float4*)(J.pos + (m & 255) * 256 + n);
            v.x += p4.x; v.y += p4.y; v.z += p4.z; v.w += p4.w;
        }
        if (relu) { v.x = fmaxf(v.x, 0.f); v.y = fmaxf(v.y, 0.f); v.z = fmaxf(v.z, 0.f); v.w = fmaxf(v.w, 0.f); }
        if (res) {
            float4 r4 = *(const float4*)(res + m * 256 + n);
            v.x += r4.x; v.y += r4.y; v.z += r4.z; v.w += r4.w;
        }
        if (maskm && maskm[m]) { v.x = 0.f; v.y = 0.f; v.z = 0.f; v.w = 0.f; }
        *(float4*)(J.C + m * 256 + n) = v;
    }
}

// one block per (b,q) — qpos reversed so heavy blocks dispatch first.
// phase1: wave w owns rows [w*64,w*64+64); per row one coalesced 1KB load of K and of tK[stm],
// lane covers dims [lane*4, lane*4+4) (inside head lane>>4); 4-step shfl reduce.
__global__ __launch_bounds__(256) void attn_kernel(
    const float* __restrict__ Q, const float* __restrict__ Kp, const float* __restrict__ Vp,
    const float* __restrict__ qres, const int* __restrict__ tm,
    const float* __restrict__ tK, const float* __restrict__ tV,
    float* __restrict__ X) {
    int qpos = 255 - (int)blockIdx.x;
    int b = blockIdx.y;
    int tid = threadIdx.x, w = tid >> 6, lane = tid & 63;
    __shared__ float qrow[256];
    __shared__ int   stm[256];
    __shared__ float p[4][256];
    __shared__ float denom[4];
    int rowbase = (b * 256 + qpos) * 256;
    qrow[tid] = Q[rowbase + tid];
    {
        int t = tm[(b * 256 + qpos) * 256 + tid];
        stm[tid] = t < 0 ? 0 : (t > 512 ? 512 : t);
    }
    __syncthreads();

    // --- phase 1: scores
    {
        int h = lane >> 4;
        const float* qr = qrow + lane * 4;
        float q0 = qr[0], q1 = qr[1], q2 = qr[2], q3 = qr[3];
        int kbase = w * 64;
#pragma unroll 2
        for (int i = 0; i < 64; ++i) {
            int k = kbase + i;
            if (k <= qpos) {
                float4 kv = *(const float4*)(Kp + ((b << 8) + k) * 256 + lane * 4);
                float4 t4 = *(const float4*)(tK + stm[k] * 256 + lane * 4);
                float partial = q0 * (kv.x + t4.x) + q1 * (kv.y + t4.y)
                              + q2 * (kv.z + t4.z) + q3 * (kv.w + t4.w);
                partial += __shfl_xor(partial, 1, 64);
                partial += __shfl_xor(partial, 2, 64);
                partial += __shfl_xor(partial, 4, 64);
                partial += __shfl_xor(partial, 8, 64);
                if ((lane & 15) == 0) p[h][k] = partial * 0.125f;
            } else {
                if ((lane & 15) == 0) p[h][k] = BIG_NEG_F;
            }
        }
    }
    __syncthreads();

    // --- softmax: wave w owns head w (4 vals/lane, shfl reduce)
    {
        float* ph = &p[w][0];
        float v0 = ph[lane], v1 = ph[lane + 64], v2 = ph[lane + 128], v3 = ph[lane + 192];
        float mx = wave_max(fmaxf(fmaxf(v0, v1), fmaxf(v2, v3)));
        float e0 = __expf(v0 - mx), e1 = __expf(v1 - mx), e2 = __expf(v2 - mx), e3 = __expf(v3 - mx);
        ph[lane] = e0; ph[lane + 64] = e1; ph[lane + 128] = e2; ph[lane + 192] = e3;
        float ssum = wave_sum(e0 + e1 + e2 + e3);
        if (lane == 0) denom[w] = ssum;
    }
    __syncthreads();

    // --- output: thread d (head h = d>>6); coalesced V/tV rows, broadcast p
    {
        int d = tid, h = tid >> 6;
        const float* ph = &p[h][0];
        float o = 0.f;
#pragma unroll 4
        for (int k2 = 0; k2 <= qpos; ++k2) {
            float pk = ph[k2];
            float v = Vp[((b << 8) + k2) * 256 + d];
            float t = tV[stm[k2] * 256 + d];
            o += pk * (v + t);
        }
        X[rowbase + d] = qres[rowbase + d] + o / denom[h];
    }
}

extern "C" void kernel_launch(void* const* d_in, const int* in_sizes, int n_in,
                              void* d_out, int out_size, void* d_ws, size_t ws_size,
                              hipStream_t stream) {
    const unsigned char* mask_raw = (const unsigned char*)d_in[0];
    const float* seq  = (const float*)d_in[1];
    const int*   tm   = (const int*)d_in[3];
    const float* Wq   = (const float*)d_in[5];
    const float* bq   = (const float*)d_in[6];
    const float* Wk   = (const float*)d_in[7];
    const float* bk   = (const float*)d_in[8];
    const float* Wv   = (const float*)d_in[9];
    const float* bv   = (const float*)d_in[10];
    const float* ln1g = (const float*)d_in[11];
    const float* ln1b = (const float*)d_in[12];
    const float* ln2g = (const float*)d_in[13];
    const float* ln2b = (const float*)d_in[14];
    const float* W1   = (const float*)d_in[15];
    const float* b1   = (const float*)d_in[16];
    const float* W2   = (const float*)d_in[17];
    const float* b2   = (const float*)d_in[18];
    const float* posK = (const float*)d_in[19];
    const float* posV = (const float*)d_in[20];
    const float* tK   = (const float*)d_in[21];
    const float* tV   = (const float*)d_in[22];
    const float* lnfg = (const float*)d_in[23];
    const float* lnfb = (const float*)d_in[24];

    const int NEL = 8 * 256 * 256;
    float* x   = (float*)d_ws;
    float* q   = x   + NEL;
    float* Qb  = q   + NEL;
    float* KpB = Qb  + NEL;
    float* VpB = KpB + NEL;
    float* x2  = VpB + NEL;
    float* hb  = x2  + NEL;
    unsigned char* mask = (unsigned char*)(hb + NEL);

    dim3 gQKV(4, 32, 3);
    dim3 gFFN(4, 32, 1);
    dim3 gAttn(256, 8);

    mask_norm_kernel<<<1, 256, 0, stream>>>(mask_raw, mask);
    prep_kernel<<<2048, 256, 0, stream>>>(seq, mask, x);
    for (int blk = 0; blk < 2; ++blk) {
        int o1 = blk * 256, oW = blk * 256 * 256;
        ln_kernel<<<2048, 256, 0, stream>>>(x, q, ln1g + o1, ln1b + o1);
        GemmJob jq = {q, Wq + oW, bq + o1, nullptr, Qb};
        GemmJob jk = {x, Wk + oW, bk + o1, posK,    KpB};
        GemmJob jv = {x, Wv + oW, bv + o1, posV,    VpB};
        gemm_kernel<<<gQKV, 256, 0, stream>>>(jq, jk, jv, nullptr, nullptr, 0);
        attn_kernel<<<gAttn, 256, 0, stream>>>(Qb, KpB, VpB, q, tm, tK, tV, x);
        ln_kernel<<<2048, 256, 0, stream>>>(x, x2, ln2g + o1, ln2b + o1);
        GemmJob jf1 = {x2, W1 + oW, b1 + o1, nullptr, hb};
        gemm_kernel<<<gFFN, 256, 0, stream>>>(jf1, jf1, jf1, nullptr, nullptr, 1);
        GemmJob jf2 = {hb, W2 + oW, b2 + o1, nullptr, x};
        gemm_kernel<<<gFFN, 256, 0, stream>>>(jf2, jf2, jf2, x2, mask, 0);
    }
    ln_kernel<<<2048, 256, 0, stream>>>(x, (float*)d_out, lnfg, lnfb);
}

// Round 7
// 353.352 us; speedup vs baseline: 1.8266x; 1.0430x over previous
//
#include <hip/hip_runtime.h>

#define BIG_NEG_F (-4294967296.0f)

__device__ __forceinline__ float wave_sum(float v) {
#pragma unroll
    for (int m = 32; m; m >>= 1) v += __shfl_xor(v, m, 64);
    return v;
}
__device__ __forceinline__ float wave_max(float v) {
#pragma unroll
    for (int m = 32; m; m >>= 1) v = fmaxf(v, __shfl_xor(v, m, 64));
    return v;
}

// Detect mask storage layout (uint8 / int32 / int64 bool) and normalize to uint8[2048].
__global__ __launch_bounds__(256) void mask_norm_kernel(const unsigned char* __restrict__ m,
                                                        unsigned char* __restrict__ out) {
    __shared__ int flags[2];
    if (threadIdx.x == 0) { flags[0] = 0; flags[1] = 0; }
    __syncthreads();
    for (int i = threadIdx.x; i < 2048; i += 256) {
        if (m[i]) {
            if (i & 3) atomicOr(&flags[0], 1);
            else if (i & 4) atomicOr(&flags[1], 1);
        }
    }
    __syncthreads();
    int mode = flags[0] ? 0 : (flags[1] ? 1 : 2);  // 0=u8, 1=i32, 2=i64
    for (int i = threadIdx.x; i < 2048; i += 256) {
        unsigned char v = (mode == 0) ? m[i] : (mode == 1) ? m[i * 4] : m[i * 8];
        out[i] = v ? 1 : 0;
    }
}

// Fused: x = seq*keep (one row per block), then q = ln1(x).
__global__ __launch_bounds__(256) void prep_ln_kernel(const float* __restrict__ seq,
                                                      const unsigned char* __restrict__ mask,
                                                      float* __restrict__ X, float* __restrict__ Q,
                                                      const float* __restrict__ g,
                                                      const float* __restrict__ be) {
    __shared__ float ws[8];
    int row = blockIdx.x, tid = threadIdx.x;
    int idx = row * 256 + tid;
    int w = tid >> 6, lane = tid & 63;
    float v = mask[row] ? 0.f : seq[idx];
    X[idx] = v;
    float s = wave_sum(v);
    if (lane == 0) ws[w] = s;
    __syncthreads();
    float mean = (ws[0] + ws[1] + ws[2] + ws[3]) * (1.f / 256.f);
    float d = v - mean;
    float s2 = wave_sum(d * d);
    if (lane == 0) ws[4 + w] = s2;
    __syncthreads();
    float var = (ws[4] + ws[5] + ws[6] + ws[7]) * (1.f / 256.f);
    Q[idx] = d / sqrtf(var + 1e-8f) * g[tid] + be[tid];
}

// row layernorm over H=256, one block per row; shfl reductions (2 barriers)
__global__ __launch_bounds__(256) void ln_kernel(const float* __restrict__ X, float* __restrict__ Y,
                                                 const float* __restrict__ g,
                                                 const float* __restrict__ be) {
    __shared__ float ws[8];
    int row = blockIdx.x, tid = threadIdx.x;
    int idx = row * 256 + tid;
    int w = tid >> 6, lane = tid & 63;
    float v = X[idx];
    float s = wave_sum(v);
    if (lane == 0) ws[w] = s;
    __syncthreads();
    float mean = (ws[0] + ws[1] + ws[2] + ws[3]) * (1.f / 256.f);
    float d = v - mean;
    float s2 = wave_sum(d * d);
    if (lane == 0) ws[4 + w] = s2;
    __syncthreads();
    float var = (ws[4] + ws[5] + ws[6] + ws[7]) * (1.f / 256.f);
    Y[idx] = d / sqrtf(var + 1e-8f) * g[tid] + be[tid];
}

struct GemmJob {
    const float* A;     // [2048,256]
    const float* W;     // [256,256] row-major (out,in)
    const float* bias;  // [256]
    const float* pos;   // [256,256] per-position add, or null
    float* C;           // [2048,256]
};

// 64x64 tile, 4x4/thread, BK=32 — for the QKV triple dispatch (grid.z picks job).
__global__ __launch_bounds__(256) void gemm64_kernel(GemmJob j0, GemmJob j1, GemmJob j2) {
    GemmJob J = (blockIdx.z == 0) ? j0 : (blockIdx.z == 1 ? j1 : j2);
    __shared__ float AsT[32][68];
    __shared__ float WsT[32][68];
    int tid = threadIdx.x;
    int n0 = blockIdx.x * 64, m0 = blockIdx.y * 64;
    int r = tid >> 4, c = tid & 15;
    int li = tid >> 2, lk = (tid & 3) * 8;
    float acc[4][4] = {};
    for (int k0 = 0; k0 < 256; k0 += 32) {
        float4 a0 = *(const float4*)(J.A + (m0 + li) * 256 + k0 + lk);
        float4 a1 = *(const float4*)(J.A + (m0 + li) * 256 + k0 + lk + 4);
        AsT[lk + 0][li] = a0.x; AsT[lk + 1][li] = a0.y; AsT[lk + 2][li] = a0.z; AsT[lk + 3][li] = a0.w;
        AsT[lk + 4][li] = a1.x; AsT[lk + 5][li] = a1.y; AsT[lk + 6][li] = a1.z; AsT[lk + 7][li] = a1.w;
        float4 w0 = *(const float4*)(J.W + (n0 + li) * 256 + k0 + lk);
        float4 w1 = *(const float4*)(J.W + (n0 + li) * 256 + k0 + lk + 4);
        WsT[lk + 0][li] = w0.x; WsT[lk + 1][li] = w0.y; WsT[lk + 2][li] = w0.z; WsT[lk + 3][li] = w0.w;
        WsT[lk + 4][li] = w1.x; WsT[lk + 5][li] = w1.y; WsT[lk + 6][li] = w1.z; WsT[lk + 7][li] = w1.w;
        __syncthreads();
#pragma unroll
        for (int kk = 0; kk < 32; ++kk) {
            float4 a = *(const float4*)&AsT[kk][r * 4];
            float4 bv = *(const float4*)&WsT[kk][c * 4];
            acc[0][0] += a.x * bv.x; acc[0][1] += a.x * bv.y; acc[0][2] += a.x * bv.z; acc[0][3] += a.x * bv.w;
            acc[1][0] += a.y * bv.x; acc[1][1] += a.y * bv.y; acc[1][2] += a.y * bv.z; acc[1][3] += a.y * bv.w;
            acc[2][0] += a.z * bv.x; acc[2][1] += a.z * bv.y; acc[2][2] += a.z * bv.z; acc[2][3] += a.z * bv.w;
            acc[3][0] += a.w * bv.x; acc[3][1] += a.w * bv.y; acc[3][2] += a.w * bv.z; acc[3][3] += a.w * bv.w;
        }
        __syncthreads();
    }
    int n = n0 + c * 4;
    float4 b4 = *(const float4*)(J.bias + n);
#pragma unroll
    for (int i = 0; i < 4; ++i) {
        int m = m0 + r * 4 + i;
        float4 v;
        v.x = acc[i][0] + b4.x; v.y = acc[i][1] + b4.y;
        v.z = acc[i][2] + b4.z; v.w = acc[i][3] + b4.w;
        if (J.pos) {
            float4 p4 = *(const float4*)(J.pos + (m & 255) * 256 + n);
            v.x += p4.x; v.y += p4.y; v.z += p4.z; v.w += p4.w;
        }
        *(float4*)(J.C + m * 256 + n) = v;
    }
}

// 32x32 tile, 2x2/thread, BK=32 — FFN GEMMs (512 blocks). relu / res / mask epilogue.
__global__ __launch_bounds__(256) void gemm32_kernel(const float* __restrict__ A,
                                                     const float* __restrict__ W,
                                                     const float* __restrict__ bias,
                                                     const float* __restrict__ res,
                                                     const unsigned char* __restrict__ maskm,
                                                     float* __restrict__ C, int relu) {
    __shared__ float AsT[32][34];
    __shared__ float WsT[32][34];
    int tid = threadIdx.x;
    int n0 = blockIdx.x * 32, m0 = blockIdx.y * 32;
    int r = tid >> 4, c = tid & 15;
    int li = tid >> 3, lk = (tid & 7) * 4;
    float acc00 = 0, acc01 = 0, acc10 = 0, acc11 = 0;
    for (int k0 = 0; k0 < 256; k0 += 32) {
        float4 av = *(const float4*)(A + (m0 + li) * 256 + k0 + lk);
        AsT[lk + 0][li] = av.x; AsT[lk + 1][li] = av.y; AsT[lk + 2][li] = av.z; AsT[lk + 3][li] = av.w;
        float4 wv = *(const float4*)(W + (n0 + li) * 256 + k0 + lk);
        WsT[lk + 0][li] = wv.x; WsT[lk + 1][li] = wv.y; WsT[lk + 2][li] = wv.z; WsT[lk + 3][li] = wv.w;
        __syncthreads();
#pragma unroll
        for (int kk = 0; kk < 32; ++kk) {
            float2 a = *(const float2*)&AsT[kk][r * 2];
            float2 b = *(const float2*)&WsT[kk][c * 2];
            acc00 += a.x * b.x; acc01 += a.x * b.y;
            acc10 += a.y * b.x; acc11 += a.y * b.y;
        }
        __syncthreads();
    }
    float accs[2][2] = {{acc00, acc01}, {acc10, acc11}};
#pragma unroll
    for (int i = 0; i < 2; ++i) {
        int m = m0 + r * 2 + i;
#pragma unroll
        for (int jj = 0; jj < 2; ++jj) {
            int n = n0 + c * 2 + jj;
            float v = accs[i][jj] + bias[n];
            if (relu) v = fmaxf(v, 0.f);
            if (res) v += res[m * 256 + n];
            if (maskm && maskm[m]) v = 0.f;
            C[m * 256 + n] = v;
        }
    }
}

// one block per (b,q) — qpos reversed so heavy blocks dispatch first.
// phase1: wave w owns rows [w*64,w*64+64); one coalesced 1KB load of K and of tK[stm] per row.
// epilogue: x_new = q + attn_out, then ln2 in-block -> X2. (x_new itself is dead downstream.)
__global__ __launch_bounds__(256) void attn_kernel(
    const float* __restrict__ Q, const float* __restrict__ Kp, const float* __restrict__ Vp,
    const float* __restrict__ qres, const int* __restrict__ tm,
    const float* __restrict__ tK, const float* __restrict__ tV,
    const float* __restrict__ g2, const float* __restrict__ b2,
    float* __restrict__ X2) {
    int qpos = 255 - (int)blockIdx.x;
    int b = blockIdx.y;
    int tid = threadIdx.x, w = tid >> 6, lane = tid & 63;
    __shared__ float qrow[256];
    __shared__ int   stm[256];
    __shared__ float p[4][264];   // 264: phase-1 writer lanes hit banks +0/+8/+16/+24
    __shared__ float denom[4];
    __shared__ float lnws[8];
    int rowbase = (b * 256 + qpos) * 256;
    qrow[tid] = Q[rowbase + tid];
    {
        int t = tm[(b * 256 + qpos) * 256 + tid];
        stm[tid] = t < 0 ? 0 : (t > 512 ? 512 : t);
    }
    __syncthreads();

    // --- phase 1: scores
    {
        int h = lane >> 4;
        const float* qr = qrow + lane * 4;
        float q0 = qr[0], q1 = qr[1], q2 = qr[2], q3 = qr[3];
        int kbase = w * 64;
#pragma unroll 2
        for (int i = 0; i < 64; ++i) {
            int k = kbase + i;
            if (k <= qpos) {
                float4 kv = *(const float4*)(Kp + ((b << 8) + k) * 256 + lane * 4);
                float4 t4 = *(const float4*)(tK + stm[k] * 256 + lane * 4);
                float partial = q0 * (kv.x + t4.x) + q1 * (kv.y + t4.y)
                              + q2 * (kv.z + t4.z) + q3 * (kv.w + t4.w);
                partial += __shfl_xor(partial, 1, 64);
                partial += __shfl_xor(partial, 2, 64);
                partial += __shfl_xor(partial, 4, 64);
                partial += __shfl_xor(partial, 8, 64);
                if ((lane & 15) == 0) p[h][k] = partial * 0.125f;
            } else {
                if ((lane & 15) == 0) p[h][k] = BIG_NEG_F;
            }
        }
    }
    __syncthreads();

    // --- softmax: wave w owns head w
    {
        float* ph = &p[w][0];
        float v0 = ph[lane], v1 = ph[lane + 64], v2 = ph[lane + 128], v3 = ph[lane + 192];
        float mx = wave_max(fmaxf(fmaxf(v0, v1), fmaxf(v2, v3)));
        float e0 = __expf(v0 - mx), e1 = __expf(v1 - mx), e2 = __expf(v2 - mx), e3 = __expf(v3 - mx);
        ph[lane] = e0; ph[lane + 64] = e1; ph[lane + 128] = e2; ph[lane + 192] = e3;
        float ssum = wave_sum(e0 + e1 + e2 + e3);
        if (lane == 0) denom[w] = ssum;
    }
    __syncthreads();

    // --- output + fused ln2
    {
        int d = tid, h = tid >> 6;
        const float* ph = &p[h][0];
        float o = 0.f;
#pragma unroll 4
        for (int k2 = 0; k2 <= qpos; ++k2) {
            float pk = ph[k2];
            float v = Vp[((b << 8) + k2) * 256 + d];
            float t = tV[stm[k2] * 256 + d];
            o += pk * (v + t);
        }
        float xv = qres[rowbase + d] + o / denom[h];
        float s = wave_sum(xv);
        if (lane == 0) lnws[w] = s;
        __syncthreads();
        float mean = (lnws[0] + lnws[1] + lnws[2] + lnws[3]) * (1.f / 256.f);
        float dd = xv - mean;
        float s2 = wave_sum(dd * dd);
        if (lane == 0) lnws[4 + w] = s2;
        __syncthreads();
        float var = (lnws[4] + lnws[5] + lnws[6] + lnws[7]) * (1.f / 256.f);
        X2[rowbase + d] = dd / sqrtf(var + 1e-8f) * g2[d] + b2[d];
    }
}

extern "C" void kernel_launch(void* const* d_in, const int* in_sizes, int n_in,
                              void* d_out, int out_size, void* d_ws, size_t ws_size,
                              hipStream_t stream) {
    const unsigned char* mask_raw = (const unsigned char*)d_in[0];
    const float* seq  = (const float*)d_in[1];
    const int*   tm   = (const int*)d_in[3];
    const float* Wq   = (const float*)d_in[5];
    const float* bq   = (const float*)d_in[6];
    const float* Wk   = (const float*)d_in[7];
    const float* bk   = (const float*)d_in[8];
    const float* Wv   = (const float*)d_in[9];
    const float* bv   = (const float*)d_in[10];
    const float* ln1g = (const float*)d_in[11];
    const float* ln1b = (const float*)d_in[12];
    const float* ln2g = (const float*)d_in[13];
    const float* ln2b = (const float*)d_in[14];
    const float* W1   = (const float*)d_in[15];
    const float* b1   = (const float*)d_in[16];
    const float* W2   = (const float*)d_in[17];
    const float* b2   = (const float*)d_in[18];
    const float* posK = (const float*)d_in[19];
    const float* posV = (const float*)d_in[20];
    const float* tK   = (const float*)d_in[21];
    const float* tV   = (const float*)d_in[22];
    const float* lnfg = (const float*)d_in[23];
    const float* lnfb = (const float*)d_in[24];

    const int NEL = 8 * 256 * 256;
    float* x   = (float*)d_ws;
    float* q   = x   + NEL;
    float* Qb  = q   + NEL;
    float* KpB = Qb  + NEL;
    float* VpB = KpB + NEL;
    float* x2  = VpB + NEL;
    float* hb  = x2  + NEL;
    unsigned char* mask = (unsigned char*)(hb + NEL);

    dim3 gQKV(4, 32, 3);
    dim3 gFFN(8, 64);
    dim3 gAttn(256, 8);

    mask_norm_kernel<<<1, 256, 0, stream>>>(mask_raw, mask);
    prep_ln_kernel<<<2048, 256, 0, stream>>>(seq, mask, x, q, ln1g, ln1b);
    for (int blk = 0; blk < 2; ++blk) {
        int o1 = blk * 256, oW = blk * 256 * 256;
        GemmJob jq = {q, Wq + oW, bq + o1, nullptr, Qb};
        GemmJob jk = {x, Wk + oW, bk + o1, posK,    KpB};
        GemmJob jv = {x, Wv + oW, bv + o1, posV,    VpB};
        gemm64_kernel<<<gQKV, 256, 0, stream>>>(jq, jk, jv);
        attn_kernel<<<gAttn, 256, 0, stream>>>(Qb, KpB, VpB, q, tm, tK, tV,
                                               ln2g + o1, ln2b + o1, x2);
        gemm32_kernel<<<gFFN, 256, 0, stream>>>(x2, W1 + oW, b1 + o1, nullptr, nullptr, hb, 1);
        gemm32_kernel<<<gFFN, 256, 0, stream>>>(hb, W2 + oW, b2 + o1, x2, mask, x, 0);
        if (blk == 0) ln_kernel<<<2048, 256, 0, stream>>>(x, q, ln1g + 256, ln1b + 256);
    }
    ln_kernel<<<2048, 256, 0, stream>>>(x, (float*)d_out, lnfg, lnfb);
}

// Round 8
// 345.822 us; speedup vs baseline: 1.8664x; 1.0218x over previous
//
#include <hip/hip_runtime.h>

#define BIG_NEG_F (-4294967296.0f)

__device__ __forceinline__ float wave_sum(float v) {
#pragma unroll
    for (int m = 32; m; m >>= 1) v += __shfl_xor(v, m, 64);
    return v;
}
__device__ __forceinline__ float wave_max(float v) {
#pragma unroll
    for (int m = 32; m; m >>= 1) v = fmaxf(v, __shfl_xor(v, m, 64));
    return v;
}

// Fused: detect mask layout (u8/i32/i64) from first 2048 bytes, normalize this row's bit,
// x = seq*keep, q = ln1(x). One block per row.
__global__ __launch_bounds__(256) void prep_ln_kernel(const float* __restrict__ seq,
                                                      const unsigned char* __restrict__ mraw,
                                                      unsigned char* __restrict__ mout,
                                                      float* __restrict__ X, float* __restrict__ Q,
                                                      const float* __restrict__ g,
                                                      const float* __restrict__ be) {
    __shared__ int flags[2];
    __shared__ float ws[8];
    int row = blockIdx.x, tid = threadIdx.x;
    if (tid == 0) { flags[0] = 0; flags[1] = 0; }
    __syncthreads();
    for (int i = tid; i < 2048; i += 256) {
        if (mraw[i]) {
            if (i & 3) atomicOr(&flags[0], 1);
            else if (i & 4) atomicOr(&flags[1], 1);
        }
    }
    __syncthreads();
    int mode = flags[0] ? 0 : (flags[1] ? 1 : 2);  // 0=u8, 1=i32, 2=i64
    unsigned char mrow = (mode == 0) ? mraw[row] : (mode == 1) ? mraw[row * 4] : mraw[row * 8];
    if (tid == 0) mout[row] = mrow ? 1 : 0;
    int idx = row * 256 + tid;
    int w = tid >> 6, lane = tid & 63;
    float v = mrow ? 0.f : seq[idx];
    X[idx] = v;
    float s = wave_sum(v);
    if (lane == 0) ws[w] = s;
    __syncthreads();
    float mean = (ws[0] + ws[1] + ws[2] + ws[3]) * (1.f / 256.f);
    float d = v - mean;
    float s2 = wave_sum(d * d);
    if (lane == 0) ws[4 + w] = s2;
    __syncthreads();
    float var = (ws[4] + ws[5] + ws[6] + ws[7]) * (1.f / 256.f);
    Q[idx] = d / sqrtf(var + 1e-8f) * g[tid] + be[tid];
}

// row layernorm over H=256, one block per row; shfl reductions (2 barriers)
__global__ __launch_bounds__(256) void ln_kernel(const float* __restrict__ X, float* __restrict__ Y,
                                                 const float* __restrict__ g,
                                                 const float* __restrict__ be) {
    __shared__ float ws[8];
    int row = blockIdx.x, tid = threadIdx.x;
    int idx = row * 256 + tid;
    int w = tid >> 6, lane = tid & 63;
    float v = X[idx];
    float s = wave_sum(v);
    if (lane == 0) ws[w] = s;
    __syncthreads();
    float mean = (ws[0] + ws[1] + ws[2] + ws[3]) * (1.f / 256.f);
    float d = v - mean;
    float s2 = wave_sum(d * d);
    if (lane == 0) ws[4 + w] = s2;
    __syncthreads();
    float var = (ws[4] + ws[5] + ws[6] + ws[7]) * (1.f / 256.f);
    Y[idx] = d / sqrtf(var + 1e-8f) * g[tid] + be[tid];
}

struct GemmJob {
    const float* A;     // [2048,256]
    const float* W;     // [256,256] row-major (out,in)
    const float* bias;  // [256]
    const float* pos;   // [256,256] per-position add, or null
    float* C;           // [2048,256]
};

// 64x64 tile, 4x4/thread, BK=32 — QKV triple dispatch (grid.z picks job).
__global__ __launch_bounds__(256) void gemm64_kernel(GemmJob j0, GemmJob j1, GemmJob j2) {
    GemmJob J = (blockIdx.z == 0) ? j0 : (blockIdx.z == 1 ? j1 : j2);
    __shared__ float AsT[32][68];
    __shared__ float WsT[32][68];
    int tid = threadIdx.x;
    int n0 = blockIdx.x * 64, m0 = blockIdx.y * 64;
    int r = tid >> 4, c = tid & 15;
    int li = tid >> 2, lk = (tid & 3) * 8;
    float acc[4][4] = {};
    for (int k0 = 0; k0 < 256; k0 += 32) {
        float4 a0 = *(const float4*)(J.A + (m0 + li) * 256 + k0 + lk);
        float4 a1 = *(const float4*)(J.A + (m0 + li) * 256 + k0 + lk + 4);
        AsT[lk + 0][li] = a0.x; AsT[lk + 1][li] = a0.y; AsT[lk + 2][li] = a0.z; AsT[lk + 3][li] = a0.w;
        AsT[lk + 4][li] = a1.x; AsT[lk + 5][li] = a1.y; AsT[lk + 6][li] = a1.z; AsT[lk + 7][li] = a1.w;
        float4 w0 = *(const float4*)(J.W + (n0 + li) * 256 + k0 + lk);
        float4 w1 = *(const float4*)(J.W + (n0 + li) * 256 + k0 + lk + 4);
        WsT[lk + 0][li] = w0.x; WsT[lk + 1][li] = w0.y; WsT[lk + 2][li] = w0.z; WsT[lk + 3][li] = w0.w;
        WsT[lk + 4][li] = w1.x; WsT[lk + 5][li] = w1.y; WsT[lk + 6][li] = w1.z; WsT[lk + 7][li] = w1.w;
        __syncthreads();
#pragma unroll
        for (int kk = 0; kk < 32; ++kk) {
            float4 a = *(const float4*)&AsT[kk][r * 4];
            float4 bv = *(const float4*)&WsT[kk][c * 4];
            acc[0][0] += a.x * bv.x; acc[0][1] += a.x * bv.y; acc[0][2] += a.x * bv.z; acc[0][3] += a.x * bv.w;
            acc[1][0] += a.y * bv.x; acc[1][1] += a.y * bv.y; acc[1][2] += a.y * bv.z; acc[1][3] += a.y * bv.w;
            acc[2][0] += a.z * bv.x; acc[2][1] += a.z * bv.y; acc[2][2] += a.z * bv.z; acc[2][3] += a.z * bv.w;
            acc[3][0] += a.w * bv.x; acc[3][1] += a.w * bv.y; acc[3][2] += a.w * bv.z; acc[3][3] += a.w * bv.w;
        }
        __syncthreads();
    }
    int n = n0 + c * 4;
    float4 b4 = *(const float4*)(J.bias + n);
#pragma unroll
    for (int i = 0; i < 4; ++i) {
        int m = m0 + r * 4 + i;
        float4 v;
        v.x = acc[i][0] + b4.x; v.y = acc[i][1] + b4.y;
        v.z = acc[i][2] + b4.z; v.w = acc[i][3] + b4.w;
        if (J.pos) {
            float4 p4 = *(const float4*)(J.pos + (m & 255) * 256 + n);
            v.x += p4.x; v.y += p4.y; v.z += p4.z; v.w += p4.w;
        }
        *(float4*)(J.C + m * 256 + n) = v;
    }
}

// 32x32 tile, 2x2/thread, BK=32 — FFN GEMMs (512 blocks). relu / res / mask epilogue.
__global__ __launch_bounds__(256) void gemm32_kernel(const float* __restrict__ A,
                                                     const float* __restrict__ W,
                                                     const float* __restrict__ bias,
                                                     const float* __restrict__ res,
                                                     const unsigned char* __restrict__ maskm,
                                                     float* __restrict__ C, int relu) {
    __shared__ float AsT[32][34];
    __shared__ float WsT[32][34];
    int tid = threadIdx.x;
    int n0 = blockIdx.x * 32, m0 = blockIdx.y * 32;
    int r = tid >> 4, c = tid & 15;
    int li = tid >> 3, lk = (tid & 7) * 4;
    float acc00 = 0, acc01 = 0, acc10 = 0, acc11 = 0;
    for (int k0 = 0; k0 < 256; k0 += 32) {
        float4 av = *(const float4*)(A + (m0 + li) * 256 + k0 + lk);
        AsT[lk + 0][li] = av.x; AsT[lk + 1][li] = av.y; AsT[lk + 2][li] = av.z; AsT[lk + 3][li] = av.w;
        float4 wv = *(const float4*)(W + (n0 + li) * 256 + k0 + lk);
        WsT[lk + 0][li] = wv.x; WsT[lk + 1][li] = wv.y; WsT[lk + 2][li] = wv.z; WsT[lk + 3][li] = wv.w;
        __syncthreads();
#pragma unroll
        for (int kk = 0; kk < 32; ++kk) {
            float2 a = *(const float2*)&AsT[kk][r * 2];
            float2 b = *(const float2*)&WsT[kk][c * 2];
            acc00 += a.x * b.x; acc01 += a.x * b.y;
            acc10 += a.y * b.x; acc11 += a.y * b.y;
        }
        __syncthreads();
    }
    float accs[2][2] = {{acc00, acc01}, {acc10, acc11}};
#pragma unroll
    for (int i = 0; i < 2; ++i) {
        int m = m0 + r * 2 + i;
#pragma unroll
        for (int jj = 0; jj < 2; ++jj) {
            int n = n0 + c * 2 + jj;
            float v = accs[i][jj] + bias[n];
            if (relu) v = fmaxf(v, 0.f);
            if (res) v += res[m * 256 + n];
            if (maskm && maskm[m]) v = 0.f;
            C[m * 256 + n] = v;
        }
    }
}

// one block per (b,q) — qpos reversed so heavy blocks dispatch first.
// phase1: wave w owns rows [w*64,w*64+64); coalesced float4 loads, 16-lane shfl dot.
// phase3: wave w owns k2 = w, w+4, ...; lane owns dims [lane*4,+4) -> float4 V/tV loads;
//         wave partials combined via LDS. epilogue: x_new = q + out, fused ln2 -> X2.
__global__ __launch_bounds__(256) void attn_kernel(
    const float* __restrict__ Q, const float* __restrict__ Kp, const float* __restrict__ Vp,
    const float* __restrict__ qres, const int* __restrict__ tm,
    const float* __restrict__ tK, const float* __restrict__ tV,
    const float* __restrict__ g2, const float* __restrict__ b2,
    float* __restrict__ X2) {
    int qpos = 255 - (int)blockIdx.x;
    int b = blockIdx.y;
    int tid = threadIdx.x, w = tid >> 6, lane = tid & 63;
    __shared__ float qrow[256];
    __shared__ int   stm[256];
    __shared__ float p[4][264];     // 264: phase-1 writer lanes spread banks
    __shared__ float opart[4][256];
    __shared__ float denom[4];
    __shared__ float lnws[8];
    int rowbase = (b * 256 + qpos) * 256;
    qrow[tid] = Q[rowbase + tid];
    {
        int t = tm[(b * 256 + qpos) * 256 + tid];
        stm[tid] = t < 0 ? 0 : (t > 512 ? 512 : t);
    }
    __syncthreads();

    // --- phase 1: scores
    {
        int h = lane >> 4;
        const float* qr = qrow + lane * 4;
        float q0 = qr[0], q1 = qr[1], q2 = qr[2], q3 = qr[3];
        int kbase = w * 64;
#pragma unroll 2
        for (int i = 0; i < 64; ++i) {
            int k = kbase + i;
            if (k <= qpos) {
                float4 kv = *(const float4*)(Kp + ((b << 8) + k) * 256 + lane * 4);
                float4 t4 = *(const float4*)(tK + stm[k] * 256 + lane * 4);
                float partial = q0 * (kv.x + t4.x) + q1 * (kv.y + t4.y)
                              + q2 * (kv.z + t4.z) + q3 * (kv.w + t4.w);
                partial += __shfl_xor(partial, 1, 64);
                partial += __shfl_xor(partial, 2, 64);
                partial += __shfl_xor(partial, 4, 64);
                partial += __shfl_xor(partial, 8, 64);
                if ((lane & 15) == 0) p[h][k] = partial * 0.125f;
            } else {
                if ((lane & 15) == 0) p[h][k] = BIG_NEG_F;
            }
        }
    }
    __syncthreads();

    // --- softmax: wave w owns head w
    {
        float* ph = &p[w][0];
        float v0 = ph[lane], v1 = ph[lane + 64], v2 = ph[lane + 128], v3 = ph[lane + 192];
        float mx = wave_max(fmaxf(fmaxf(v0, v1), fmaxf(v2, v3)));
        float e0 = __expf(v0 - mx), e1 = __expf(v1 - mx), e2 = __expf(v2 - mx), e3 = __expf(v3 - mx);
        ph[lane] = e0; ph[lane + 64] = e1; ph[lane + 128] = e2; ph[lane + 192] = e3;
        float ssum = wave_sum(e0 + e1 + e2 + e3);
        if (lane == 0) denom[w] = ssum;
    }
    __syncthreads();

    // --- phase 3: PV with float4 lanes, waves split k2
    {
        int hh = lane >> 4;                 // head of this lane's 4 dims
        float4 o = {0.f, 0.f, 0.f, 0.f};
        for (int k2 = w; k2 <= qpos; k2 += 4) {
            float pk = p[hh][k2];
            float4 v = *(const float4*)(Vp + ((b << 8) + k2) * 256 + lane * 4);
            float4 t = *(const float4*)(tV + stm[k2] * 256 + lane * 4);
            o.x += pk * (v.x + t.x);
            o.y += pk * (v.y + t.y);
            o.z += pk * (v.z + t.z);
            o.w += pk * (v.w + t.w);
        }
        *(float4*)&opart[w][lane * 4] = o;
    }
    __syncthreads();

    // --- combine + fused ln2
    {
        int d = tid, h = tid >> 6;
        float tot = opart[0][d] + opart[1][d] + opart[2][d] + opart[3][d];
        float xv = qres[rowbase + d] + tot / denom[h];
        float s = wave_sum(xv);
        if (lane == 0) lnws[w] = s;
        __syncthreads();
        float mean = (lnws[0] + lnws[1] + lnws[2] + lnws[3]) * (1.f / 256.f);
        float dd = xv - mean;
        float s2 = wave_sum(dd * dd);
        if (lane == 0) lnws[4 + w] = s2;
        __syncthreads();
        float var = (lnws[4] + lnws[5] + lnws[6] + lnws[7]) * (1.f / 256.f);
        X2[rowbase + d] = dd / sqrtf(var + 1e-8f) * g2[d] + b2[d];
    }
}

extern "C" void kernel_launch(void* const* d_in, const int* in_sizes, int n_in,
                              void* d_out, int out_size, void* d_ws, size_t ws_size,
                              hipStream_t stream) {
    const unsigned char* mask_raw = (const unsigned char*)d_in[0];
    const float* seq  = (const float*)d_in[1];
    const int*   tm   = (const int*)d_in[3];
    const float* Wq   = (const float*)d_in[5];
    const float* bq   = (const float*)d_in[6];
    const float* Wk   = (const float*)d_in[7];
    const float* bk   = (const float*)d_in[8];
    const float* Wv   = (const float*)d_in[9];
    const float* bv   = (const float*)d_in[10];
    const float* ln1g = (const float*)d_in[11];
    const float* ln1b = (const float*)d_in[12];
    const float* ln2g = (const float*)d_in[13];
    const float* ln2b = (const float*)d_in[14];
    const float* W1   = (const float*)d_in[15];
    const float* b1   = (const float*)d_in[16];
    const float* W2   = (const float*)d_in[17];
    const float* b2   = (const float*)d_in[18];
    const float* posK = (const float*)d_in[19];
    const float* posV = (const float*)d_in[20];
    const float* tK   = (const float*)d_in[21];
    const float* tV   = (const float*)d_in[22];
    const float* lnfg = (const float*)d_in[23];
    const float* lnfb = (const float*)d_in[24];

    const int NEL = 8 * 256 * 256;
    float* x   = (float*)d_ws;
    float* q   = x   + NEL;
    float* Qb  = q   + NEL;
    float* KpB = Qb  + NEL;
    float* VpB = KpB + NEL;
    float* x2  = VpB + NEL;
    float* hb  = x2  + NEL;
    unsigned char* mask = (unsigned char*)(hb + NEL);

    dim3 gQKV(4, 32, 3);
    dim3 gFFN(8, 64);
    dim3 gAttn(256, 8);

    prep_ln_kernel<<<2048, 256, 0, stream>>>(seq, mask_raw, mask, x, q, ln1g, ln1b);
    for (int blk = 0; blk < 2; ++blk) {
        int o1 = blk * 256, oW = blk * 256 * 256;
        GemmJob jq = {q, Wq + oW, bq + o1, nullptr, Qb};
        GemmJob jk = {x, Wk + oW, bk + o1, posK,    KpB};
        GemmJob jv = {x, Wv + oW, bv + o1, posV,    VpB};
        gemm64_kernel<<<gQKV, 256, 0, stream>>>(jq, jk, jv);
        attn_kernel<<<gAttn, 256, 0, stream>>>(Qb, KpB, VpB, q, tm, tK, tV,
                                               ln2g + o1, ln2b + o1, x2);
        gemm32_kernel<<<gFFN, 256, 0, stream>>>(x2, W1 + oW, b1 + o1, nullptr, nullptr, hb, 1);
        gemm32_kernel<<<gFFN, 256, 0, stream>>>(hb, W2 + oW, b2 + o1, x2, mask, x, 0);
        if (blk == 0) ln_kernel<<<2048, 256, 0, stream>>>(x, q, ln1g + 256, ln1b + 256);
    }
    ln_kernel<<<2048, 256, 0, stream>>>(x, (float*)d_out, lnfg, lnfb);
}